// Round 7
// baseline (119.735 us; speedup 1.0000x reference)
//
#include <hip/hip_runtime.h>
#include <math.h>

#define NN 100000          // nodes
#define NE 1600000         // edges
#define NBKT 391           // buckets of 256 nodes: (NN+255)/256
#define EPB 4096           // edges per partition chunk
#define NPB ((NE + EPB - 1) / EPB)        // 391 chunks
#define RSPLIT 4                          // bucket-range split per chunk (occupancy)
#define BPR ((NBKT + RSPLIT - 1) / RSPLIT)// 98 buckets per range
#define TOTC (NBKT * NPB)                 // 152,881 scanned cells
#define SBLK 2048                         // scan elems per block
#define NSB ((TOTC + SBLK - 1) / SBLK)    // 75 scan blocks
#define LBUF 6144          // per-bucket LDS entry cap (mean 4092, +32 sigma)

typedef unsigned int uint;
typedef unsigned short ushort;
typedef __attribute__((ext_vector_type(8))) short bfx8;
typedef __attribute__((ext_vector_type(4))) float f32x4;

static __device__ __forceinline__ ushort f2bf(float f) {
  uint u = __float_as_uint(f);
  uint r = (u + 0x7fffu + ((u >> 16) & 1u)) >> 16;   // RNE
  return (ushort)r;
}
static __device__ __forceinline__ float bf2f(ushort v) {
  return __uint_as_float((uint)v << 16);
}

// ---------------- Kernel A: h = x @ W^T via bf16 MFMA, fused s_src/s_dst ----
__global__ __launch_bounds__(256) void k_h(
    const float* __restrict__ x, const float* __restrict__ W,
    const float* __restrict__ a_src, const float* __restrict__ a_dst,
    ushort* __restrict__ h16, float* __restrict__ ssrc, float* __restrict__ sdst)
{
  __shared__ __align__(16) ushort xs[128 * 128];  // 32KB
  __shared__ __align__(16) ushort ws[64 * 128];   // 16KB
  const int t = threadIdx.x;
  const int base = blockIdx.x * 128;
  const float4* x4 = (const float4*)x;
  const float4* W4 = (const float4*)W;

#pragma unroll
  for (int q = 0; q < 16; ++q) {
    int f = q * 256 + t;
    int row = f >> 5, c4 = f & 31;
    float4 v = make_float4(0.f, 0.f, 0.f, 0.f);
    if (base + row < NN) v = x4[(size_t)(base + row) * 32 + c4];
    ushort4 pk = make_ushort4(f2bf(v.x), f2bf(v.y), f2bf(v.z), f2bf(v.w));
    int byte = row * 256 + ((c4 * 8) ^ ((row & 7) << 4));
    *(ushort4*)((char*)xs + byte) = pk;
  }
#pragma unroll
  for (int q = 0; q < 8; ++q) {
    int f = q * 256 + t;
    int row = f >> 5, c4 = f & 31;
    float4 v = W4[f];
    ushort4 pk = make_ushort4(f2bf(v.x), f2bf(v.y), f2bf(v.z), f2bf(v.w));
    int byte = row * 256 + ((c4 * 8) ^ ((row & 7) << 4));
    *(ushort4*)((char*)ws + byte) = pk;
  }
  __syncthreads();

  const int wid = t >> 6;
  const int lane = t & 63;
  const int lg = lane >> 4;    // k-group / C row group
  const int lr = lane & 15;    // A row / B col / C col

  f32x4 acc[2][4];
#pragma unroll
  for (int mg = 0; mg < 2; ++mg)
#pragma unroll
    for (int ng = 0; ng < 4; ++ng) acc[mg][ng] = (f32x4){0.f, 0.f, 0.f, 0.f};

#pragma unroll
  for (int ks = 0; ks < 4; ++ks) {
    int kb = ks * 64 + lg * 16;
    bfx8 afr[2], bfr[4];
#pragma unroll
    for (int mg = 0; mg < 2; ++mg) {
      int row = wid * 32 + mg * 16 + lr;
      afr[mg] = *(const bfx8*)((const char*)xs + row * 256 + (kb ^ ((row & 7) << 4)));
    }
#pragma unroll
    for (int ng = 0; ng < 4; ++ng) {
      int row = ng * 16 + lr;
      bfr[ng] = *(const bfx8*)((const char*)ws + row * 256 + (kb ^ ((row & 7) << 4)));
    }
#pragma unroll
    for (int mg = 0; mg < 2; ++mg)
#pragma unroll
      for (int ng = 0; ng < 4; ++ng)
        acc[mg][ng] = __builtin_amdgcn_mfma_f32_16x16x32_bf16(afr[mg], bfr[ng], acc[mg][ng], 0, 0, 0);
  }

  float as_[4], ad_[4];
#pragma unroll
  for (int ng = 0; ng < 4; ++ng) { as_[ng] = a_src[ng * 16 + lr]; ad_[ng] = a_dst[ng * 16 + lr]; }
#pragma unroll
  for (int mg = 0; mg < 2; ++mg) {
#pragma unroll
    for (int r = 0; r < 4; ++r) {
      int node = base + wid * 32 + mg * 16 + lg * 4 + r;
      float ps = 0.f, pd = 0.f;
#pragma unroll
      for (int ng = 0; ng < 4; ++ng) { ps += acc[mg][ng][r] * as_[ng]; pd += acc[mg][ng][r] * ad_[ng]; }
#pragma unroll
      for (int m = 1; m < 16; m <<= 1) { ps += __shfl_xor(ps, m); pd += __shfl_xor(pd, m); }
      if (lr == 0 && node < NN) { ssrc[node] = ps; sdst[node] = pd; }
      if (node < NN) {
#pragma unroll
        for (int ng = 0; ng < 4; ++ng)
          h16[(size_t)node * 64 + ng * 16 + lr] = f2bf(acc[mg][ng][r]);
      }
    }
  }
}

// ---------------- per-block bucket histogram (no global atomics) ----------------
__global__ __launch_bounds__(256) void k_hist(const int* __restrict__ ei,
                                              int* __restrict__ cnt)
{
  __shared__ int hh[NBKT];
  int t = threadIdx.x, blk = blockIdx.x;
  for (int i = t; i < NBKT; i += 256) hh[i] = 0;
  __syncthreads();
  int base = blk * EPB;
#pragma unroll
  for (int q = 0; q < EPB / 256; ++q) {
    int e = base + q * 256 + t;
    if (e < NE) atomicAdd(&hh[ei[NE + e] >> 8], 1);
  }
  __syncthreads();
  for (int i = t; i < NBKT; i += 256) cnt[i * NPB + blk] = hh[i];
}

// ---------------- 3-pass grid-parallel exclusive scan of cnt[TOTC] --------------
__global__ __launch_bounds__(256) void k_scanA(const int* __restrict__ cnt,
                                               int* __restrict__ partials)
{
  __shared__ int sm[256];
  int t = threadIdx.x, b = blockIdx.x;
  const int4* c4 = (const int4*)(cnt + b * SBLK + t * 8);
  int4 u = c4[0], v = c4[1];
  sm[t] = u.x + u.y + u.z + u.w + v.x + v.y + v.z + v.w;
  __syncthreads();
  for (int s = 128; s > 0; s >>= 1) { if (t < s) sm[t] += sm[t + s]; __syncthreads(); }
  if (t == 0) partials[b] = sm[0];
}

__global__ __launch_bounds__(128) void k_scanB(int* __restrict__ partials,
                                               int* __restrict__ boff,
                                               int* __restrict__ offsets)
{
  __shared__ int sm[128];
  int t = threadIdx.x;
  int v = (t < NSB) ? partials[t] : 0;
  sm[t] = v;
  __syncthreads();
  for (int off = 1; off < 128; off <<= 1) {
    int u = (t >= off) ? sm[t - off] : 0;
    __syncthreads();
    sm[t] += u;
    __syncthreads();
  }
  if (t < NSB) partials[t] = sm[t] - v;   // exclusive
  if (t == 0) { boff[NBKT] = NE; offsets[NN] = NE; }
}

__global__ __launch_bounds__(256) void k_scanC(int* __restrict__ cnt,
                                               const int* __restrict__ partials,
                                               int* __restrict__ boff)
{
  __shared__ int sm[256];
  int t = threadIdx.x, b = blockIdx.x;
  int base = b * SBLK + t * 8;
  int4* c4 = (int4*)(cnt + base);
  int4 u = c4[0], v = c4[1];
  int tot = u.x + u.y + u.z + u.w + v.x + v.y + v.z + v.w;
  sm[t] = tot;
  __syncthreads();
  for (int off = 1; off < 256; off <<= 1) {
    int w = (t >= off) ? sm[t - off] : 0;
    __syncthreads();
    sm[t] += w;
    __syncthreads();
  }
  int run = partials[b] + sm[t] - tot;
  int e[8] = {u.x, u.y, u.z, u.w, v.x, v.y, v.z, v.w};
  int ex[8];
#pragma unroll
  for (int k = 0; k < 8; ++k) { ex[k] = run; run += e[k]; }
#pragma unroll
  for (int k = 0; k < 8; ++k) {
    int idx = base + k;
    if (idx < TOTC && idx % NPB == 0) boff[idx / NPB] = ex[k];
  }
  c4[0] = make_int4(ex[0], ex[1], ex[2], ex[3]);
  c4[1] = make_int4(ex[4], ex[5], ex[6], ex[7]);
}

// ---------------- partition pass: (chunk, bucket-quarter) per block -------------
// RSPLIT blocks share one chunk; each handles 98 of the 391 buckets -> 4x the
// waves in flight vs one-block-per-chunk (occupancy was 11%, latency-bound).
__global__ __launch_bounds__(256) void k_part(const int* __restrict__ ei,
                                              const int* __restrict__ cnt,
                                              const float* __restrict__ ssrc,
                                              const float* __restrict__ sdst,
                                              int2* __restrict__ stage)
{
  __shared__ int cur[BPR];
  int t = threadIdx.x;
  int blk  = blockIdx.x >> 2;          // chunk (RSPLIT == 4)
  int roff = (blockIdx.x & 3) * BPR;   // bucket range [roff, roff+BPR)
  for (int i = t; i < BPR; i += 256) {
    int b = roff + i;
    if (b < NBKT) cur[i] = cnt[b * NPB + blk];
  }
  __syncthreads();
  int base = blk * EPB;
#pragma unroll
  for (int q = 0; q < EPB / 256; ++q) {
    int e = base + q * 256 + t;
    if (e < NE) {
      int dst = ei[NE + e];
      int b = (dst >> 8) - roff;
      if ((uint)b < (uint)BPR) {
        int src = ei[e];
        int pos = atomicAdd(&cur[b], 1);
        float v = ssrc[src] + sdst[dst];
        v = (v >= 0.f) ? v : 0.2f * v;           // LeakyReLU(0.2)
        v = fminf(fmaxf(v, -10.f), 10.f);        // clip
        stage[pos] = make_int2(src | ((dst & 255) << 24), __float_as_int(__expf(v)));
      }
    }
  }
}

// ---------------- place: per-bucket node-sort in LDS, coalesced CSR out ---------
__global__ __launch_bounds__(256) void k_place(const int* __restrict__ boff,
                                               const int2* __restrict__ stage,
                                               int* __restrict__ offsets,
                                               int2* __restrict__ csr)
{
  __shared__ int2 lbuf[LBUF];
  __shared__ int cnt2[256];
  __shared__ int cur2[256];
  int b = blockIdx.x, t = threadIdx.x;
  int e_beg = boff[b], e_end = boff[b + 1];
  int m = e_end - e_beg;

  cnt2[t] = 0;
  __syncthreads();
  for (int i = t; i < m; i += 256)
    atomicAdd(&cnt2[((uint)stage[e_beg + i].x) >> 24], 1);
  __syncthreads();

  int v0 = cnt2[t];
  for (int off = 1; off < 256; off <<= 1) {
    int u = (t >= off) ? cnt2[t - off] : 0;
    __syncthreads();
    cnt2[t] += u;
    __syncthreads();
  }
  int excl = cnt2[t] - v0;
  cur2[t] = excl;
  int node = (b << 8) + t;
  if (node < NN) offsets[node] = e_beg + excl;
  __syncthreads();

  for (int i = t; i < m; i += 256) {
    int2 v = stage[e_beg + i];
    int dl = ((uint)v.x) >> 24;
    int slot = atomicAdd(&cur2[dl], 1);
    lbuf[slot] = make_int2(v.x & 0xFFFFFF, v.y);
  }
  __syncthreads();
  for (int i = t; i < m; i += 256) csr[e_beg + i] = lbuf[i];
}

// ---------------- aggregation: 16 lanes/node, 4 nodes/wave, unroll-4 ------------
__global__ __launch_bounds__(256) void k_agg(const int* __restrict__ offsets,
                                             const int2* __restrict__ csr,
                                             const ushort* __restrict__ h16,
                                             float* __restrict__ out)
{
  int t = blockIdx.x * 256 + threadIdx.x;
  int node = t >> 4;
  int l4 = t & 15;
  if (node >= NN) return;
  int beg = offsets[node];
  int end = offsets[node + 1];
  const uint2* h2 = (const uint2*)h16;
  float ax = 0.f, ay = 0.f, az = 0.f, aw = 0.f, den = 0.f;
  int last = end - 1;
  for (int j = beg; j < end; j += 4) {
    int2 e0 = csr[j];
    int2 e1 = csr[min(j + 1, last)];
    int2 e2 = csr[min(j + 2, last)];
    int2 e3 = csr[min(j + 3, last)];
    float a0 = __int_as_float(e0.y);
    float a1 = (j + 1 < end) ? __int_as_float(e1.y) : 0.f;
    float a2 = (j + 2 < end) ? __int_as_float(e2.y) : 0.f;
    float a3 = (j + 3 < end) ? __int_as_float(e3.y) : 0.f;
    uint2 q0 = h2[e0.x * 16 + l4];
    uint2 q1 = h2[e1.x * 16 + l4];
    uint2 q2 = h2[e2.x * 16 + l4];
    uint2 q3 = h2[e3.x * 16 + l4];
    den += (a0 + a1) + (a2 + a3);
    ax += a0 * bf2f((ushort)(q0.x & 0xffff)) + a1 * bf2f((ushort)(q1.x & 0xffff))
        + a2 * bf2f((ushort)(q2.x & 0xffff)) + a3 * bf2f((ushort)(q3.x & 0xffff));
    ay += a0 * bf2f((ushort)(q0.x >> 16)) + a1 * bf2f((ushort)(q1.x >> 16))
        + a2 * bf2f((ushort)(q2.x >> 16)) + a3 * bf2f((ushort)(q3.x >> 16));
    az += a0 * bf2f((ushort)(q0.y & 0xffff)) + a1 * bf2f((ushort)(q1.y & 0xffff))
        + a2 * bf2f((ushort)(q2.y & 0xffff)) + a3 * bf2f((ushort)(q3.y & 0xffff));
    aw += a0 * bf2f((ushort)(q0.y >> 16)) + a1 * bf2f((ushort)(q1.y >> 16))
        + a2 * bf2f((ushort)(q2.y >> 16)) + a3 * bf2f((ushort)(q3.y >> 16));
  }
  float inv = 1.f / (den + 1e-9f);
  float4 o;
  o.x = ax * inv; o.y = ay * inv; o.z = az * inv; o.w = aw * inv;
  ((float4*)out)[node * 16 + l4] = o;
}

extern "C" void kernel_launch(void* const* d_in, const int* in_sizes, int n_in,
                              void* d_out, int out_size, void* d_ws, size_t ws_size,
                              hipStream_t stream)
{
  const float* x     = (const float*)d_in[0];
  const int*   ei    = (const int*)d_in[1];
  const float* W     = (const float*)d_in[2];
  const float* a_src = (const float*)d_in[3];
  const float* a_dst = (const float*)d_in[4];
  float* out = (float*)d_out;

  char* p = (char*)d_ws;
  auto alloc = [&](size_t bytes) -> char* {
    char* r = p;
    p += (bytes + 255) & ~(size_t)255;
    return r;
  };
  ushort* h16    = (ushort*)alloc((size_t)NN * 64 * 2);
  float* ssrc    = (float*)alloc((size_t)NN * 4);
  float* sdst    = (float*)alloc((size_t)NN * 4);
  int*   offsets = (int*)alloc((size_t)(NN + 1) * 4);
  int*   cnt     = (int*)alloc((size_t)NSB * SBLK * 4);   // padded past TOTC
  int*   boff    = (int*)alloc((size_t)(NBKT + 1) * 4);
  int*   partials= (int*)alloc((size_t)NSB * 4);
  int2*  stage   = (int2*)alloc((size_t)NE * 8);
  int2*  csr     = (int2*)alloc((size_t)NE * 8);

  k_h<<<(NN + 127) / 128, 256, 0, stream>>>(x, W, a_src, a_dst, h16, ssrc, sdst);
  k_hist<<<NPB, 256, 0, stream>>>(ei, cnt);
  k_scanA<<<NSB, 256, 0, stream>>>(cnt, partials);
  k_scanB<<<1, 128, 0, stream>>>(partials, boff, offsets);
  k_scanC<<<NSB, 256, 0, stream>>>(cnt, partials, boff);
  k_part<<<NPB * RSPLIT, 256, 0, stream>>>(ei, cnt, ssrc, sdst, stage);
  k_place<<<NBKT, 256, 0, stream>>>(boff, stage, offsets, csr);
  k_agg<<<((size_t)NN * 16 + 255) / 256, 256, 0, stream>>>(offsets, csr, h16, out);
}

// Round 8
// 105.926 us; speedup vs baseline: 1.1304x; 1.1304x over previous
//
#include <hip/hip_runtime.h>
#include <math.h>

#define NN 100000          // nodes
#define NE 1600000         // edges
#define NBKT 391           // buckets of 256 nodes: (NN+255)/256
#define LPS  (NBKT + 1)    // lpre row stride (392)
#define EPB 2048           // edges per sort chunk
#define NPB ((NE + EPB - 1) / EPB)        // 782 chunks
#define TOTC (NBKT * NPB)                 // 305,762 cells (bucket-major)
#define SBLK 2048                         // scan elems per block
#define NSB ((TOTC + SBLK - 1) / SBLK)    // 150 scan blocks
#define LBUF 6144          // per-bucket LDS entry cap (mean 4092, +32 sigma)

typedef unsigned int uint;
typedef unsigned short ushort;
typedef __attribute__((ext_vector_type(8))) short bfx8;
typedef __attribute__((ext_vector_type(4))) float f32x4;

static __device__ __forceinline__ ushort f2bf(float f) {
  uint u = __float_as_uint(f);
  uint r = (u + 0x7fffu + ((u >> 16) & 1u)) >> 16;   // RNE
  return (ushort)r;
}
static __device__ __forceinline__ float bf2f(ushort v) {
  return __uint_as_float((uint)v << 16);
}
static __device__ __forceinline__ bfx8 cvt8(float4 a, float4 b) {
  bfx8 r;
  r[0] = (short)f2bf(a.x); r[1] = (short)f2bf(a.y);
  r[2] = (short)f2bf(a.z); r[3] = (short)f2bf(a.w);
  r[4] = (short)f2bf(b.x); r[5] = (short)f2bf(b.y);
  r[6] = (short)f2bf(b.z); r[7] = (short)f2bf(b.w);
  return r;
}

// ---------------- Kernel A: h = x @ W^T via bf16 MFMA, fused s_src/s_dst ----
// 64 nodes/block, 4 waves x 16 rows. x: direct global->register (rows read once
// per block, loads hoisted for MLP, no staging barrier). W: 16KB bf16 LDS,
// XOR-swizzled (T2) exactly as the verified R5 kernel.
__global__ __launch_bounds__(256) void k_h(
    const float* __restrict__ x, const float* __restrict__ W,
    const float* __restrict__ a_src, const float* __restrict__ a_dst,
    ushort* __restrict__ h16, float* __restrict__ ssrc, float* __restrict__ sdst)
{
  __shared__ __align__(16) ushort ws[64 * 128];   // 16KB
  const int t = threadIdx.x;
  const int base = blockIdx.x * 64;
  const float4* x4 = (const float4*)x;
  const float4* W4 = (const float4*)W;

#pragma unroll
  for (int q = 0; q < 8; ++q) {
    int f = q * 256 + t;
    int row = f >> 5, c4 = f & 31;
    float4 v = W4[f];
    ushort4 pk = make_ushort4(f2bf(v.x), f2bf(v.y), f2bf(v.z), f2bf(v.w));
    int byte = row * 256 + ((c4 * 8) ^ ((row & 7) << 4));
    *(ushort4*)((char*)ws + byte) = pk;
  }

  const int wid = t >> 6;
  const int lane = t & 63;
  const int lg = lane >> 4;    // k-group / C row group
  const int lr = lane & 15;    // A row / B col / C col

  const int node = base + wid * 16 + lr;
  const bool ok = node < NN;
  const float4* xr = x4 + (size_t)node * 32;

  // hoist this lane's 8 x float4 loads (full K for its row)
  float4 xa[4][2];
#pragma unroll
  for (int ks = 0; ks < 4; ++ks) {
    xa[ks][0] = ok ? xr[ks * 8 + lg * 2]     : make_float4(0.f, 0.f, 0.f, 0.f);
    xa[ks][1] = ok ? xr[ks * 8 + lg * 2 + 1] : make_float4(0.f, 0.f, 0.f, 0.f);
  }
  __syncthreads();

  f32x4 acc[4];
#pragma unroll
  for (int ng = 0; ng < 4; ++ng) acc[ng] = (f32x4){0.f, 0.f, 0.f, 0.f};

#pragma unroll
  for (int ks = 0; ks < 4; ++ks) {
    int kb = ks * 64 + lg * 16;
    bfx8 af = cvt8(xa[ks][0], xa[ks][1]);
    bfx8 bfr[4];
#pragma unroll
    for (int ng = 0; ng < 4; ++ng) {
      int row = ng * 16 + lr;
      bfr[ng] = *(const bfx8*)((const char*)ws + row * 256 + (kb ^ ((row & 7) << 4)));
    }
#pragma unroll
    for (int ng = 0; ng < 4; ++ng)
      acc[ng] = __builtin_amdgcn_mfma_f32_16x16x32_bf16(af, bfr[ng], acc[ng], 0, 0, 0);
  }

  float as_[4], ad_[4];
#pragma unroll
  for (int ng = 0; ng < 4; ++ng) { as_[ng] = a_src[ng * 16 + lr]; ad_[ng] = a_dst[ng * 16 + lr]; }
#pragma unroll
  for (int r = 0; r < 4; ++r) {
    int nout = base + wid * 16 + lg * 4 + r;
    float ps = 0.f, pd = 0.f;
#pragma unroll
    for (int ng = 0; ng < 4; ++ng) { ps += acc[ng][r] * as_[ng]; pd += acc[ng][r] * ad_[ng]; }
#pragma unroll
    for (int m = 1; m < 16; m <<= 1) { ps += __shfl_xor(ps, m); pd += __shfl_xor(pd, m); }
    if (lr == 0 && nout < NN) { ssrc[nout] = ps; sdst[nout] = pd; }
    if (nout < NN) {
#pragma unroll
      for (int ng = 0; ng < 4; ++ng)
        h16[(size_t)nout * 64 + ng * 16 + lr] = f2bf(acc[ng][r]);
    }
  }
}

// ---------------- k_sort: per-chunk bucket sort in LDS, coalesced stage out -----
// Replaces k_hist + k_part. One block = one 2048-edge chunk. Emits:
//   stage[c*EPB + i]      sorted-by-bucket chunk entries {src|dl<<24, ssrc[src]}
//   lpre[c*LPS + b]       within-chunk exclusive bucket prefix (+[NBKT]=chunk len)
//   cnt[b*NPB + c]        bucket-major counts (input to the global scan)
__global__ __launch_bounds__(256) void k_sort(const int* __restrict__ ei,
                                              const float* __restrict__ ssrc,
                                              int* __restrict__ cnt,
                                              int* __restrict__ lpre,
                                              int2* __restrict__ stage)
{
  __shared__ int hh[NBKT];
  __shared__ int sums[256];
  __shared__ int2 sbuf[EPB];    // 16KB
  const int t = threadIdx.x, c = blockIdx.x;
  for (int i = t; i < NBKT; i += 256) hh[i] = 0;
  __syncthreads();

  const int base = c * EPB;
  const int nloc = min(EPB, NE - base);
  int my_src[EPB / 256], my_dst[EPB / 256];
#pragma unroll
  for (int q = 0; q < EPB / 256; ++q) {
    int e = base + q * 256 + t;
    if (e < NE) {
      my_src[q] = ei[e];
      my_dst[q] = ei[NE + e];
      atomicAdd(&hh[my_dst[q] >> 8], 1);
    } else my_dst[q] = -1;
  }
  __syncthreads();

  // exclusive scan of hh[391], 2 elems/thread
  int i0 = 2 * t, i1 = 2 * t + 1;
  int v0 = (i0 < NBKT) ? hh[i0] : 0;
  int v1 = (i1 < NBKT) ? hh[i1] : 0;
  sums[t] = v0 + v1;
  __syncthreads();
  for (int off = 1; off < 256; off <<= 1) {
    int u = (t >= off) ? sums[t - off] : 0;
    __syncthreads();
    sums[t] += u;
    __syncthreads();
  }
  int ex0 = sums[t] - (v0 + v1);
  if (i0 < NBKT) {
    hh[i0] = ex0;
    lpre[c * LPS + i0] = ex0;
    cnt[i0 * NPB + c] = v0;
  }
  if (i1 < NBKT) {
    hh[i1] = ex0 + v0;
    lpre[c * LPS + i1] = ex0 + v0;
    cnt[i1 * NPB + c] = v1;
  }
  if (t == 0) lpre[c * LPS + NBKT] = nloc;
  __syncthreads();

  // scatter into sbuf (LDS) with ssrc gather
#pragma unroll
  for (int q = 0; q < EPB / 256; ++q) {
    if (my_dst[q] >= 0) {
      int dst = my_dst[q], src = my_src[q];
      int pos = atomicAdd(&hh[dst >> 8], 1);
      sbuf[pos] = make_int2(src | ((dst & 255) << 24), __float_as_int(ssrc[src]));
    }
  }
  __syncthreads();
#pragma unroll
  for (int q = 0; q < EPB / 256; ++q) {
    int i = q * 256 + t;
    if (i < nloc) stage[base + i] = sbuf[i];
  }
}

// ---------------- 3-pass grid-parallel exclusive scan of cnt[TOTC] --------------
__global__ __launch_bounds__(256) void k_scanA(const int* __restrict__ cnt,
                                               int* __restrict__ partials)
{
  __shared__ int sm[256];
  int t = threadIdx.x, b = blockIdx.x;
  const int4* c4 = (const int4*)(cnt + b * SBLK + t * 8);
  int4 u = c4[0], v = c4[1];
  sm[t] = u.x + u.y + u.z + u.w + v.x + v.y + v.z + v.w;
  __syncthreads();
  for (int s = 128; s > 0; s >>= 1) { if (t < s) sm[t] += sm[t + s]; __syncthreads(); }
  if (t == 0) partials[b] = sm[0];
}

__global__ __launch_bounds__(256) void k_scanB(int* __restrict__ partials,
                                               int* __restrict__ boff,
                                               int* __restrict__ offsets)
{
  __shared__ int sm[256];
  int t = threadIdx.x;
  int v = (t < NSB) ? partials[t] : 0;
  sm[t] = v;
  __syncthreads();
  for (int off = 1; off < 256; off <<= 1) {
    int u = (t >= off) ? sm[t - off] : 0;
    __syncthreads();
    sm[t] += u;
    __syncthreads();
  }
  if (t < NSB) partials[t] = sm[t] - v;   // exclusive
  if (t == 0) { boff[NBKT] = NE; offsets[NN] = NE; }
}

__global__ __launch_bounds__(256) void k_scanC(int* __restrict__ cnt,
                                               const int* __restrict__ partials,
                                               int* __restrict__ boff)
{
  __shared__ int sm[256];
  int t = threadIdx.x, b = blockIdx.x;
  int base = b * SBLK + t * 8;
  int4* c4 = (int4*)(cnt + base);
  int4 u = c4[0], v = c4[1];
  int tot = u.x + u.y + u.z + u.w + v.x + v.y + v.z + v.w;
  sm[t] = tot;
  __syncthreads();
  for (int off = 1; off < 256; off <<= 1) {
    int w = (t >= off) ? sm[t - off] : 0;
    __syncthreads();
    sm[t] += w;
    __syncthreads();
  }
  int run = partials[b] + sm[t] - tot;
  int e[8] = {u.x, u.y, u.z, u.w, v.x, v.y, v.z, v.w};
  int ex[8];
#pragma unroll
  for (int k = 0; k < 8; ++k) { ex[k] = run; run += e[k]; }
#pragma unroll
  for (int k = 0; k < 8; ++k) {
    int idx = base + k;
    if (idx < TOTC && idx % NPB == 0) boff[idx / NPB] = ex[k];
  }
  c4[0] = make_int4(ex[0], ex[1], ex[2], ex[3]);
  c4[1] = make_int4(ex[4], ex[5], ex[6], ex[7]);
}

// ---------------- k_place: gather bucket runs, node-sort in LDS, CSR + offsets --
__global__ __launch_bounds__(256) void k_place(const int* __restrict__ boff,
                                               const int* __restrict__ cnt,   // post-scan outpos
                                               const int* __restrict__ lpre,
                                               const int2* __restrict__ stage,
                                               const float* __restrict__ sdst,
                                               int* __restrict__ offsets,
                                               int2* __restrict__ csr)
{
  __shared__ int2 lbuf[LBUF];   // 48KB
  __shared__ int nh[256];
  __shared__ int cur[256];
  __shared__ float sdl[256];
  const int b = blockIdx.x, t = threadIdx.x;
  const int e_beg = boff[b], e_end = boff[b + 1];
  const int m = e_end - e_beg;

  // phase 1: gather this bucket's runs from all chunks
  for (int c = t; c < NPB; c += 256) {
    int lp = lpre[c * LPS + b];
    int lq = lpre[c * LPS + b + 1];
    int outp = cnt[b * NPB + c] - e_beg;
    int sin = c * EPB + lp;
    for (int k = 0; k < lq - lp; ++k) lbuf[outp + k] = stage[sin + k];
  }
  nh[t] = 0;
  int node = (b << 8) + t;
  sdl[t] = (node < NN) ? sdst[node] : 0.f;
  __syncthreads();

  // phase 2: node histogram + scan -> offsets
  for (int i = t; i < m; i += 256)
    atomicAdd(&nh[((uint)lbuf[i].x) >> 24], 1);
  __syncthreads();
  int v0 = nh[t];
  for (int off = 1; off < 256; off <<= 1) {
    int u = (t >= off) ? nh[t - off] : 0;
    __syncthreads();
    nh[t] += u;
    __syncthreads();
  }
  int excl = nh[t] - v0;
  cur[t] = excl;
  if (node < NN) offsets[node] = e_beg + excl;
  __syncthreads();

  // phase 3: alpha + node-sorted CSR write (scatter within this bucket's window)
  for (int i = t; i < m; i += 256) {
    int2 v = lbuf[i];
    int dl = ((uint)v.x) >> 24;
    int slot = atomicAdd(&cur[dl], 1);
    float e = __int_as_float(v.y) + sdl[dl];
    e = (e >= 0.f) ? e : 0.2f * e;           // LeakyReLU(0.2)
    e = fminf(fmaxf(e, -10.f), 10.f);        // clip
    csr[e_beg + slot] = make_int2(v.x & 0xFFFFFF, __float_as_int(__expf(e)));
  }
}

// ---------------- aggregation: 16 lanes/node, 4 nodes/wave, unroll-4 ------------
__global__ __launch_bounds__(256) void k_agg(const int* __restrict__ offsets,
                                             const int2* __restrict__ csr,
                                             const ushort* __restrict__ h16,
                                             float* __restrict__ out)
{
  int t = blockIdx.x * 256 + threadIdx.x;
  int node = t >> 4;
  int l4 = t & 15;
  if (node >= NN) return;
  int beg = offsets[node];
  int end = offsets[node + 1];
  const uint2* h2 = (const uint2*)h16;
  float ax = 0.f, ay = 0.f, az = 0.f, aw = 0.f, den = 0.f;
  int last = end - 1;
  for (int j = beg; j < end; j += 4) {
    int2 e0 = csr[j];
    int2 e1 = csr[min(j + 1, last)];
    int2 e2 = csr[min(j + 2, last)];
    int2 e3 = csr[min(j + 3, last)];
    float a0 = __int_as_float(e0.y);
    float a1 = (j + 1 < end) ? __int_as_float(e1.y) : 0.f;
    float a2 = (j + 2 < end) ? __int_as_float(e2.y) : 0.f;
    float a3 = (j + 3 < end) ? __int_as_float(e3.y) : 0.f;
    uint2 q0 = h2[e0.x * 16 + l4];
    uint2 q1 = h2[e1.x * 16 + l4];
    uint2 q2 = h2[e2.x * 16 + l4];
    uint2 q3 = h2[e3.x * 16 + l4];
    den += (a0 + a1) + (a2 + a3);
    ax += a0 * bf2f((ushort)(q0.x & 0xffff)) + a1 * bf2f((ushort)(q1.x & 0xffff))
        + a2 * bf2f((ushort)(q2.x & 0xffff)) + a3 * bf2f((ushort)(q3.x & 0xffff));
    ay += a0 * bf2f((ushort)(q0.x >> 16)) + a1 * bf2f((ushort)(q1.x >> 16))
        + a2 * bf2f((ushort)(q2.x >> 16)) + a3 * bf2f((ushort)(q3.x >> 16));
    az += a0 * bf2f((ushort)(q0.y & 0xffff)) + a1 * bf2f((ushort)(q1.y & 0xffff))
        + a2 * bf2f((ushort)(q2.y & 0xffff)) + a3 * bf2f((ushort)(q3.y & 0xffff));
    aw += a0 * bf2f((ushort)(q0.y >> 16)) + a1 * bf2f((ushort)(q1.y >> 16))
        + a2 * bf2f((ushort)(q2.y >> 16)) + a3 * bf2f((ushort)(q3.y >> 16));
  }
  float inv = 1.f / (den + 1e-9f);
  float4 o;
  o.x = ax * inv; o.y = ay * inv; o.z = az * inv; o.w = aw * inv;
  ((float4*)out)[node * 16 + l4] = o;
}

extern "C" void kernel_launch(void* const* d_in, const int* in_sizes, int n_in,
                              void* d_out, int out_size, void* d_ws, size_t ws_size,
                              hipStream_t stream)
{
  const float* x     = (const float*)d_in[0];
  const int*   ei    = (const int*)d_in[1];
  const float* W     = (const float*)d_in[2];
  const float* a_src = (const float*)d_in[3];
  const float* a_dst = (const float*)d_in[4];
  float* out = (float*)d_out;

  char* p = (char*)d_ws;
  auto alloc = [&](size_t bytes) -> char* {
    char* r = p;
    p += (bytes + 255) & ~(size_t)255;
    return r;
  };
  ushort* h16    = (ushort*)alloc((size_t)NN * 64 * 2);
  float* ssrc    = (float*)alloc((size_t)NN * 4);
  float* sdst    = (float*)alloc((size_t)NN * 4);
  int*   offsets = (int*)alloc((size_t)(NN + 1) * 4);
  int*   cnt     = (int*)alloc((size_t)NSB * SBLK * 4);   // padded past TOTC
  int*   lpre    = (int*)alloc((size_t)NPB * LPS * 4);
  int*   boff    = (int*)alloc((size_t)(NBKT + 1) * 4);
  int*   partials= (int*)alloc((size_t)NSB * 4);
  int2*  stage   = (int2*)alloc((size_t)NPB * EPB * 8);
  int2*  csr     = (int2*)alloc((size_t)NE * 8);

  k_h<<<(NN + 63) / 64, 256, 0, stream>>>(x, W, a_src, a_dst, h16, ssrc, sdst);
  k_sort<<<NPB, 256, 0, stream>>>(ei, ssrc, cnt, lpre, stage);
  k_scanA<<<NSB, 256, 0, stream>>>(cnt, partials);
  k_scanB<<<1, 256, 0, stream>>>(partials, boff, offsets);
  k_scanC<<<NSB, 256, 0, stream>>>(cnt, partials, boff);
  k_place<<<NBKT, 256, 0, stream>>>(boff, cnt, lpre, stage, sdst, offsets, csr);
  k_agg<<<((size_t)NN * 16 + 255) / 256, 256, 0, stream>>>(offsets, csr, h16, out);
}